// Round 8
// baseline (80.165 us; speedup 1.0000x reference)
//
#include <hip/hip_runtime.h>

#define BLOCK 1024
#define CHUNK 1024
#define CHUNKS_PER_BLOCK 4
#define ROWS_PER_BLOCK (CHUNK * CHUNKS_PER_BLOCK)
#define HALF_FLOATS (512 * 17)   // 8704 floats = 34816 B per half-buffer

typedef unsigned int uint_t;

__device__ __forceinline__ unsigned short f2bf(float f) {   // RNE f32->bf16
    uint_t u = __builtin_bit_cast(uint_t, f);
    u = u + 0x7FFFu + ((u >> 16) & 1u);
    return (unsigned short)(u >> 16);
}
__device__ __forceinline__ float bflo(uint_t u) { uint_t v = u << 16;         return __builtin_bit_cast(float, v); }
__device__ __forceinline__ float bfhi(uint_t u) { uint_t v = u & 0xFFFF0000u; return __builtin_bit_cast(float, v); }

// async global->LDS DMA, 16B/lane; LDS dest is wave-uniform base + lane*16 (HW adds lane term)
__device__ __forceinline__ void dma16(const float* g, float* l) {
    __builtin_amdgcn_global_load_lds((const __attribute__((address_space(1))) void*)g,
                                     (__attribute__((address_space(3))) void*)l, 16, 0, 0);
}

__device__ __forceinline__ void idx_of(float x, float lo, float inv_range_times_nm1,
                                       int n, int& i0, float& f) {
    float t = (x - lo) * inv_range_times_nm1;
    t = fminf(fmaxf(t, 0.0f), (float)(n - 1));
    int i = (int)t;
    if (i > n - 2) i = n - 2;
    i0 = i;
    f = t - (float)i;
}

__global__ __launch_bounds__(BLOCK, 4)
void nlplant_kernel(const float* __restrict__ xu,
                    const float* __restrict__ tab3,
                    const float* __restrict__ tab2,
                    const float* __restrict__ tab1,
                    const float* __restrict__ tab_eta,
                    float* __restrict__ out, long long nrows)
{
    // LDS budget (159360 B of 160 KiB):
    //  s_t3a : tab3 ch0-3 bf16-packed, 2 dwords/corner, b64 reads   15200 B
    //  s_t3b : tab3 ch4 f32 flat (bank = idx%32, uniform)            7600 B
    //  s_tab2: f32 stride-20 (R5 proven: b128 starts cycle groups)  30400 B
    //  s_tab1: f32 stride-21 (coprime 32) + eta tail                 1712 B
    //  s_buf : 3 rotating half-chunk IO buffers (512 rows x 17)    104448 B
    __shared__ uint_t s_t3a[1900 * 2];
    __shared__ float  s_t3b[1900];
    __shared__ float  s_tab2[380 * 20];
    __shared__ float  s_tab1[428];
    __shared__ float  s_buf[3][HALF_FLOATS];

    const int tid  = threadIdx.x;
    const int lane = tid & 63, wid = tid >> 6;
    const long long base = (long long)blockIdx.x * ROWS_PER_BLOCK;

    // ---------------- prologue: issue chunk-0 DMA, then stage tables ----------
    {
        long long rem = nrows - base;
        const int rows0 = rem >= CHUNK ? CHUNK : (rem > 0 ? (int)rem : 0);
        const float* g = xu + base * 17;
        if (rows0 == CHUNK) {
            for (int s = wid; s < 34; s += 16) dma16(g + s * 256 + lane * 4, s_buf[0] + s * 256);
            for (int s = wid; s < 34; s += 16) dma16(g + HALF_FLOATS + s * 256 + lane * 4, s_buf[1] + s * 256);
        } else {
            const int tot = rows0 * 17;
            for (int k = tid; k < tot; k += BLOCK) {
                float v = g[k];
                if (k < HALF_FLOATS) s_buf[0][k] = v; else s_buf[1][k - HALF_FLOATS] = v;
            }
        }
    }
    for (int idx = tid; idx < 1900; idx += BLOCK) {     // tab3 src [c][a][b][e]; [a][b][e] == idx order
        float c0 = tab3[idx], c1 = tab3[1900 + idx], c2 = tab3[3800 + idx],
              c3 = tab3[5700 + idx], c4 = tab3[7600 + idx];
        s_t3a[2 * idx]     = (uint_t)f2bf(c0) | ((uint_t)f2bf(c1) << 16);
        s_t3a[2 * idx + 1] = (uint_t)f2bf(c2) | ((uint_t)f2bf(c3) << 16);
        s_t3b[idx] = c4;
    }
    for (int k = tid; k < 6080; k += BLOCK) {           // tab2 src [c][a][b]
        int ib = k % 19; int r = k / 19; int ia = r % 20; int ch = r / 20;
        s_tab2[(ia * 19 + ib) * 20 + ch] = tab2[k];
    }
    for (int k = tid; k < 420; k += BLOCK) {            // tab1 src [c][a]
        int ia = k % 20; int ch = k / 20;
        s_tab1[ia * 21 + ch] = tab1[k];
    }
    if (tid < 5) s_tab1[420 + tid] = tab_eta[tid];
    __syncthreads();   // drains chunk-0 DMA (flew under table staging) + table writes

    // ---------------- chunk loop: compute k while DMA'ing k+1 -----------------
    const float g_ = 32.17f, m_ = 636.94f, Bs = 30.0f, S = 300.0f, cbar = 11.32f;
    const float xcgr = 0.35f, xcg = 0.25f;
    const float Jy = 55814.0f, Jxz = 982.0f, Jz = 63100.0f, Jx = 9496.0f;
    const float r2d = 57.29577951308232f;

    for (int c = 0; c < CHUNKS_PER_BLOCK; ++c) {
        const long long cb = base + (long long)c * CHUNK;
        if (cb >= nrows) break;                       // block-uniform
        long long rem = nrows - cb;
        const int rows = rem >= CHUNK ? CHUNK : (int)rem;

        float* X = s_buf[(2 * c) % 3];                // holds rows [0,512)
        float* Y = s_buf[(2 * c + 1) % 3];            // holds rows [512,1024); reused for out-staging
        float* Z = s_buf[(2 * c + 2) % 3];            // DMA target: chunk c+1 half-1

        // -- read my row into registers (cols 0,1 unused by the physics) --
        const int l = tid & 511;
        const float* srcrow = (tid < 512) ? &X[l * 17] : &Y[l * 17];
        const bool active = tid < rows;
        float x[17];
#pragma unroll
        for (int j = 0; j < 17; ++j) x[j] = 1.0f;
        if (active) {
#pragma unroll
            for (int j = 2; j < 17; ++j) x[j] = srcrow[j];
        }
        __syncthreads();                               // X,Y consumed -> free

        // -- prefetch chunk c+1: h1 -> Z, h2 -> X (both fly under compute) --
        const long long nb = cb + CHUNK;
        if (c + 1 < CHUNKS_PER_BLOCK && nb < nrows) {
            long long nrem = nrows - nb;
            const int nrow = nrem >= CHUNK ? CHUNK : (int)nrem;
            const float* g = xu + nb * 17;
            if (nrow == CHUNK) {
                for (int s = wid; s < 34; s += 16) dma16(g + s * 256 + lane * 4, Z + s * 256);
                for (int s = wid; s < 34; s += 16) dma16(g + HALF_FLOATS + s * 256 + lane * 4, X + s * 256);
            } else {
                const int tot = nrow * 17;
                for (int k = tid; k < tot; k += BLOCK) {
                    float v = g[k];
                    if (k < HALF_FLOATS) Z[k] = v; else X[k - HALF_FLOATS] = v;
                }
            }
        }

        // ---------------- per-row physics ----------------------------------
        const float alt = x[2], phi = x[3], theta = x[4], psi = x[5];
        const float vt = fmaxf(x[6], 0.01f);
        const float alpha = x[7], beta = x[8];
        const float a_deg = alpha * r2d, b_deg = beta * r2d;
        const float P = x[9], Q = x[10], R = x[11];
        const float T = x[12], el = x[13], ail = x[14], rud = x[15], lef = x[16];

        const float dail = ail * (1.0f / 21.5f);
        const float drud = rud * (1.0f / 30.0f);
        const float dlef = 1.0f - lef * (1.0f / 25.0f);

        const float tfac = 1.0f - 7.03e-6f * alt;
        const float rho = 0.002377f * __expf(4.14f * __logf(tfac));
        const float qbar = 0.5f * rho * vt * vt;

        float sa, ca, sb, cb_, st, ct, sphi, cphi, spsi, cpsi;
        __sincosf(alpha, &sa, &ca);
        __sincosf(beta, &sb, &cb_);
        __sincosf(theta, &st, &ct);
        __sincosf(phi, &sphi, &cphi);
        __sincosf(psi, &spsi, &cpsi);
        const float tt = st / ct;

        int ia, ib, ie; float fa, fb, fe;
        idx_of(a_deg, -20.0f, 19.0f / 110.0f, 20, ia, fa);
        idx_of(b_deg, -30.0f, 18.0f / 60.0f, 19, ib, fb);
        idx_of(el,    -25.0f,  4.0f / 50.0f,  5, ie, fe);

        const float wa[2] = {1.0f - fa, fa};
        const float wb[2] = {1.0f - fb, fb};
        const float we[2] = {1.0f - fe, fe};

        float v3c[5]  = {0, 0, 0, 0, 0};
        float v30c[5] = {0, 0, 0, 0, 0};
#pragma unroll
        for (int di = 0; di < 2; ++di) {
#pragma unroll
            for (int dj = 0; dj < 2; ++dj) {
                const float wab = wa[di] * wb[dj];
                const int pb3 = ((ia + di) * 19 + (ib + dj)) * 5;
#pragma unroll
                for (int dk = 0; dk < 2; ++dk) {
                    const int idx = pb3 + ie + dk;
                    const uint2 qp = *reinterpret_cast<const uint2*>(&s_t3a[idx << 1]);
                    const float w = wab * we[dk];
                    v3c[0] += bflo(qp.x) * w; v3c[1] += bfhi(qp.x) * w;
                    v3c[2] += bflo(qp.y) * w; v3c[3] += bfhi(qp.y) * w;
                    v3c[4] += s_t3b[idx] * w;
                }
                const int zidx = pb3 + 2;              // el = 0 -> ie = 2, fe = 0 exactly
                const uint2 q0 = *reinterpret_cast<const uint2*>(&s_t3a[zidx << 1]);
                v30c[0] += bflo(q0.x) * wab; v30c[1] += bfhi(q0.x) * wab;
                v30c[2] += bflo(q0.y) * wab; v30c[3] += bfhi(q0.y) * wab;
                v30c[4] += s_t3b[zidx] * wab;
            }
        }

        float v2c[16];
        {
            const float w00 = wa[0] * wb[0], w01 = wa[0] * wb[1];
            const float w10 = wa[1] * wb[0], w11 = wa[1] * wb[1];
            const float4* p00 = reinterpret_cast<const float4*>(&s_tab2[(ia * 19 + ib) * 20]);
            const float4* p01 = reinterpret_cast<const float4*>(&s_tab2[(ia * 19 + ib + 1) * 20]);
            const float4* p10 = reinterpret_cast<const float4*>(&s_tab2[((ia + 1) * 19 + ib) * 20]);
            const float4* p11 = reinterpret_cast<const float4*>(&s_tab2[((ia + 1) * 19 + ib + 1) * 20]);
#pragma unroll
            for (int q = 0; q < 4; ++q) {
                const float4 a = p00[q], b = p01[q], d = p10[q], e = p11[q];
                v2c[4 * q + 0] = a.x * w00 + b.x * w01 + d.x * w10 + e.x * w11;
                v2c[4 * q + 1] = a.y * w00 + b.y * w01 + d.y * w10 + e.y * w11;
                v2c[4 * q + 2] = a.z * w00 + b.z * w01 + d.z * w10 + e.z * w11;
                v2c[4 * q + 3] = a.w * w00 + b.w * w01 + d.w * w10 + e.w * w11;
            }
        }

        float v1c[21];
        {
            const float* r0 = &s_tab1[ia * 21];
            const float* r1 = &s_tab1[(ia + 1) * 21];
#pragma unroll
            for (int ch = 0; ch < 21; ++ch) v1c[ch] = r0[ch] * wa[0] + r1[ch] * wa[1];
        }
        const float eta_el = s_tab1[420 + ie] * we[0] + s_tab1[421 + ie] * we[1];

        const float Cx = v3c[0], Cz = v3c[1], Cm = v3c[2], Cn = v3c[3], Cl = v3c[4];
        const float Cy = v2c[0];
        const float Cxq = v1c[0], Cyr = v1c[1], Cyp = v1c[2], Czq = v1c[3], Clr = v1c[4];
        const float Clp = v1c[5], Cmq = v1c[6], Cnr = v1c[7], Cnp = v1c[8];
        const float dCxq_lef = v1c[9], dCyr_lef = v1c[10], dCyp_lef = v1c[11];
        const float dCzq_lef = v1c[12], dClr_lef = v1c[13], dClp_lef = v1c[14];
        const float dCmq_lef = v1c[15], dCnr_lef = v1c[16], dCnp_lef = v1c[17];
        const float dCnbeta = v1c[18], dClbeta = v1c[19], dCm = v1c[20];

        const float d_Cx_lef = v2c[1] - v30c[0];
        const float d_Cz_lef = v2c[2] - v30c[1];
        const float d_Cm_lef = v2c[3] - v30c[2];
        const float d_Cy_lef = v2c[4] - v2c[0];
        const float d_Cn_lef = v2c[5] - v30c[3];
        const float d_Cl_lef = v2c[6] - v30c[4];
        const float d_Cy_r30 = v2c[7] - v2c[0];
        const float d_Cn_r30 = v2c[8] - v30c[3];
        const float d_Cl_r30 = v2c[9] - v30c[4];
        const float d_Cy_a20 = v2c[10] - v2c[0];
        const float d_Cy_a20_lef = v2c[11] - v2c[4];
        const float d_Cn_a20 = v2c[12] - v30c[3];
        const float d_Cn_a20_lef = v2c[13] - v2c[5];
        const float d_Cl_a20 = v2c[14] - v30c[4];
        const float d_Cl_a20_lef = v2c[15] - v2c[6];

        const float U = vt * ca * cb_, V = vt * sb, W = vt * sa * cb_;
        const float o0 = U * (ct * cpsi) + V * (sphi * cpsi * st - cphi * spsi) + W * (cphi * st * cpsi + sphi * spsi);
        const float o1 = U * (ct * spsi) + V * (sphi * spsi * st + cphi * cpsi) + W * (cphi * st * spsi - sphi * cpsi);
        const float o2 = U * st - V * (sphi * ct) - W * (cphi * ct);
        const float o3 = P + tt * (Q * sphi + R * cphi);
        const float o4 = Q * cphi - R * sphi;
        const float o5 = (Q * sphi + R * cphi) / ct;

        const float c2v = 1.0f / (2.0f * vt);
        const float cq = cbar * c2v, bq = Bs * c2v;
        const float dXdQ = cq * (Cxq + dCxq_lef * dlef);
        const float Cx_tot = Cx + d_Cx_lef * dlef + dXdQ * Q;
        const float dZdQ = cq * (Czq + dCzq_lef * dlef);
        const float Cz_tot = Cz + d_Cz_lef * dlef + dZdQ * Q;
        const float dMdQ = cq * (Cmq + dCmq_lef * dlef);
        const float Cm_tot = Cm * eta_el + Cz_tot * (xcgr - xcg) + d_Cm_lef * dlef + dMdQ * Q + dCm;
        const float dYdail = d_Cy_a20 + d_Cy_a20_lef * dlef;
        const float dYdR = bq * (Cyr + dCyr_lef * dlef);
        const float dYdP = bq * (Cyp + dCyp_lef * dlef);
        const float Cy_tot = Cy + d_Cy_lef * dlef + dYdail * dail + d_Cy_r30 * drud + dYdR * R + dYdP * P;
        const float dNdail = d_Cn_a20 + d_Cn_a20_lef * dlef;
        const float dNdR = bq * (Cnr + dCnr_lef * dlef);
        const float dNdP = bq * (Cnp + dCnp_lef * dlef);
        const float Cn_tot = Cn + d_Cn_lef * dlef - Cy_tot * ((xcgr - xcg) * (cbar / Bs))
                           + dNdail * dail + d_Cn_r30 * drud + dNdR * R + dNdP * P + dCnbeta * b_deg;
        const float dLdail = d_Cl_a20 + d_Cl_a20_lef * dlef;
        const float dLdR = bq * (Clr + dClr_lef * dlef);
        const float dLdP = bq * (Clp + dClp_lef * dlef);
        const float Cl_tot = Cl + d_Cl_lef * dlef + dLdail * dail + d_Cl_r30 * drud
                           + dLdR * R + dLdP * P + dClbeta * b_deg;

        const float qS = qbar * S;
        const float qS_m = qS * (1.0f / m_);
        const float Udot = R * V - Q * W - g_ * st + qS_m * Cx_tot + T * (1.0f / m_);
        const float Vdot = P * W - R * U + g_ * ct * sphi + qS_m * Cy_tot;
        const float Wdot = Q * U - P * V + g_ * ct * cphi + qS_m * Cz_tot;
        const float o6 = (U * Udot + V * Vdot + W * Wdot) / vt;
        const float o7 = (U * Wdot - W * Udot) / (U * U + W * W);
        const float o8 = (Vdot * vt - V * o6) / (vt * vt * cb_);

        const float L_tot = Cl_tot * qS * Bs;
        const float M_tot = Cm_tot * qS * cbar;
        const float N_tot = Cn_tot * qS * Bs;
        const float denom = Jx * Jz - Jxz * Jxz;
        const float inv_denom = 1.0f / denom;
        const float o9  = (Jz * L_tot + Jxz * N_tot - (Jz * (Jz - Jy) + Jxz * Jxz) * Q * R
                          + Jxz * (Jx - Jy + Jz) * P * Q) * inv_denom;       // Heng = 0
        const float o10 = (M_tot + (Jz - Jx) * P * R - Jxz * (P * P - R * R)) * (1.0f / Jy);
        const float o11 = (Jx * N_tot + Jxz * L_tot + (Jx * (Jx - Jy) + Jxz * Jxz) * P * Q
                          - Jxz * (Jx - Jy + Jz) * Q * R) * inv_denom;

        const float o[12] = {o0, o1, o2, o3, o4, o5, o6, o7, o8, o9, o10, o11};

        // -- stage + drain outputs via Y (free: its input was consumed; not a DMA target) --
#pragma unroll
        for (int h = 0; h < 2; ++h) {
            if ((tid >> 9) == h && active) {
#pragma unroll
                for (int j = 0; j < 17; ++j) Y[l * 17 + j] = (j < 12) ? o[j] : 0.0f;
            }
            __syncthreads();   // also drains this wave's DMA (already flown under compute)
            const long long ob = (cb + (long long)h * 512) * 17;
            int hrows = rows - h * 512; hrows = hrows < 0 ? 0 : (hrows > 512 ? 512 : hrows);
            const int dw = hrows * 17;
            if (dw == HALF_FLOATS) {
                float4* dst = reinterpret_cast<float4*>(out + ob);
                const float4* s4 = reinterpret_cast<const float4*>(Y);
                for (int k = tid; k < HALF_FLOATS / 4; k += BLOCK) dst[k] = s4[k];
            } else {
                for (int k = tid; k < dw; k += BLOCK) out[ob + k] = Y[k];
            }
            __syncthreads();
        }
    }
}

extern "C" void kernel_launch(void* const* d_in, const int* in_sizes, int n_in,
                              void* d_out, int out_size, void* d_ws, size_t ws_size,
                              hipStream_t stream) {
    const float* xu      = (const float*)d_in[0];
    const float* tab3    = (const float*)d_in[1];
    const float* tab2    = (const float*)d_in[2];
    const float* tab1    = (const float*)d_in[3];
    const float* tab_eta = (const float*)d_in[4];
    float* out = (float*)d_out;

    const long long nrows = in_sizes[0] / 17;
    const int grid = (int)((nrows + ROWS_PER_BLOCK - 1) / ROWS_PER_BLOCK);
    nlplant_kernel<<<grid, BLOCK, 0, stream>>>(xu, tab3, tab2, tab1, tab_eta, out, nrows);
}

// Round 9
// 64.142 us; speedup vs baseline: 1.2498x; 1.2498x over previous
//
#include <hip/hip_runtime.h>

#define BLOCK 1024
#define ROWS_PER_BLOCK 1024

__device__ __forceinline__ void idx_of(float x, float lo, float inv_range_times_nm1,
                                       int n, int& i0, float& f) {
    float t = (x - lo) * inv_range_times_nm1;
    t = fminf(fmaxf(t, 0.0f), (float)(n - 1));
    int i = (int)t;                 // t >= 0, truncation == floor
    if (i > n - 2) i = n - 2;
    i0 = i;
    f = t - (float)i;
}

__global__ __launch_bounds__(BLOCK, 1)
void nlplant_kernel(const float* __restrict__ xu,
                    const float* __restrict__ tab3,
                    const float* __restrict__ tab2,
                    const float* __restrict__ tab1,
                    const float* __restrict__ tab_eta,
                    float* __restrict__ out, int nrows)
{
    // R5-proven bank layouts:
    //  s_t3a ch0-3 : stride 4  -> b128 start group = idx%8, uniform over 32 banks
    //  s_t3b ch4   : flat      -> bank = idx%32, uniform
    //  s_tab2      : stride 20 -> b128 starts cycle all 8 bank-groups (80B row, 16B aligned)
    //  s_tab1      : stride 21 (coprime 32) -> scalar reads conflict-free; eta tail @420
    // Staging is div/mod-free: channel is a compile-time unroll constant, idx = tid.
    __shared__ __align__(16) float s_t3a[1900 * 4];     // 30400B
    __shared__ __align__(16) float s_t3b[1900];         //  7600B
    __shared__ __align__(16) float s_tab2[380 * 20];    // 30400B
    __shared__ __align__(16) float s_tab1[428];         //  1712B
    __shared__ __align__(16) float s_io[512 * 17];      // 34816B  (total ~105KB)

    const int tid = threadIdx.x;

    // ---------------- stage tables: coalesced reads, zero div/mod -------------
#pragma unroll
    for (int c = 0; c < 5; ++c) {                  // tab3 src [c][a][b][e]; idx == [a][b][e]
        for (int idx = tid; idx < 1900; idx += BLOCK) {
            const float v = tab3[c * 1900 + idx];
            if (c < 4) s_t3a[(idx << 2) + c] = v;
            else       s_t3b[idx] = v;
        }
    }
    if (tid < 380) {
#pragma unroll
        for (int ch = 0; ch < 16; ++ch)            // tab2 src [c][a][b]; tid == [a][b]
            s_tab2[tid * 20 + ch] = tab2[ch * 380 + tid];
    }
    if (tid < 420) {                               // tab1 src [c][a]: tid = ch*20+ia
        const int ch = tid / 20;                   // single const-divide (magic mul)
        const int ia = tid - ch * 20;
        s_tab1[ia * 21 + ch] = tab1[tid];
    }
    if (tid < 5) s_tab1[420 + tid] = tab_eta[tid];

    // ---------------- stage input rows, phase A (rows [base, base+512)) -------
    const int base = blockIdx.x * ROWS_PER_BLOCK;
    int remA = nrows - base;           if (remA < 0) remA = 0;
    const int rowsA = remA < 512 ? remA : 512;
    int remB = nrows - base - 512;     if (remB < 0) remB = 0;
    const int rowsB = remB < 512 ? remB : 512;

    if (rowsA == 512) {
        const float4* src = reinterpret_cast<const float4*>(xu + (size_t)base * 17);
        float4* dst = reinterpret_cast<float4*>(s_io);
        for (int k = tid; k < 2176; k += BLOCK) dst[k] = src[k];
    } else {
        for (int k = tid; k < rowsA * 17; k += BLOCK) s_io[k] = xu[(size_t)base * 17 + k];
    }
    __syncthreads();

    const int half = tid >> 9;
    const int l = tid & 511;
    const bool active = (half == 0) ? (l < rowsA) : (l < rowsB);

    float x[17];
#pragma unroll
    for (int j = 0; j < 17; ++j) x[j] = 1.0f;   // benign defaults for inactive lanes

    if (half == 0 && l < rowsA) {
#pragma unroll
        for (int j = 2; j < 17; ++j) x[j] = s_io[l * 17 + j];   // cols 0,1 unused
    }
    __syncthreads();

    // phase B (rows [base+512, base+1024))
    if (rowsB == 512) {
        const float4* src = reinterpret_cast<const float4*>(xu + (size_t)(base + 512) * 17);
        float4* dst = reinterpret_cast<float4*>(s_io);
        for (int k = tid; k < 2176; k += BLOCK) dst[k] = src[k];
    } else {
        for (int k = tid; k < rowsB * 17; k += BLOCK) s_io[k] = xu[(size_t)(base + 512) * 17 + k];
    }
    __syncthreads();
    if (half == 1 && l < rowsB) {
#pragma unroll
        for (int j = 2; j < 17; ++j) x[j] = s_io[l * 17 + j];
    }

    // ---------------- per-row physics ----------------------------------------
    const float g = 32.17f, m_ = 636.94f, Bs = 30.0f, S = 300.0f, cbar = 11.32f;
    const float xcgr = 0.35f, xcg = 0.25f;
    const float Jy = 55814.0f, Jxz = 982.0f, Jz = 63100.0f, Jx = 9496.0f;
    const float r2d = 57.29577951308232f;

    const float alt = x[2], phi = x[3], theta = x[4], psi = x[5];
    const float vt = fmaxf(x[6], 0.01f);
    const float alpha = x[7], beta = x[8];
    const float a_deg = alpha * r2d, b_deg = beta * r2d;
    const float P = x[9], Q = x[10], R = x[11];
    const float T = x[12], el = x[13], ail = x[14], rud = x[15], lef = x[16];

    const float dail = ail * (1.0f / 21.5f);
    const float drud = rud * (1.0f / 30.0f);
    const float dlef = 1.0f - lef * (1.0f / 25.0f);

    const float tfac = 1.0f - 7.03e-6f * alt;
    const float rho = 0.002377f * __expf(4.14f * __logf(tfac));
    const float qbar = 0.5f * rho * vt * vt;

    float sa, ca, sb, cb, st, ct, sphi, cphi, spsi, cpsi;
    __sincosf(alpha, &sa, &ca);
    __sincosf(beta, &sb, &cb);
    __sincosf(theta, &st, &ct);
    __sincosf(phi, &sphi, &cphi);
    __sincosf(psi, &spsi, &cpsi);
    const float tt = st / ct;

    int ia, ib, ie; float fa, fb, fe;
    idx_of(a_deg, -20.0f, 19.0f / 110.0f, 20, ia, fa);
    idx_of(b_deg, -30.0f, 18.0f / 60.0f, 19, ib, fb);
    idx_of(el,    -25.0f,  4.0f / 50.0f,  5, ie, fe);

    const float wa[2] = {1.0f - fa, fa};
    const float wb[2] = {1.0f - fb, fb};
    const float we[2] = {1.0f - fe, fe};

    // --- trilinear v3 (5ch) and bilinear-at-e=2 v30 (5ch) ---
    float v3c[5]  = {0, 0, 0, 0, 0};
    float v30c[5] = {0, 0, 0, 0, 0};
#pragma unroll
    for (int di = 0; di < 2; ++di) {
#pragma unroll
        for (int dj = 0; dj < 2; ++dj) {
            const float wab = wa[di] * wb[dj];
            const int pb3 = ((ia + di) * 19 + (ib + dj)) * 5;
#pragma unroll
            for (int dk = 0; dk < 2; ++dk) {
                const int idx = pb3 + ie + dk;
                const float4 q = *reinterpret_cast<const float4*>(&s_t3a[idx << 2]);
                const float q4 = s_t3b[idx];
                const float w = wab * we[dk];
                v3c[0] += q.x * w; v3c[1] += q.y * w; v3c[2] += q.z * w;
                v3c[3] += q.w * w; v3c[4] += q4 * w;
            }
            const int zidx = pb3 + 2;       // el = 0 -> ie = 2, fe = 0 exactly
            const float4 q0 = *reinterpret_cast<const float4*>(&s_t3a[zidx << 2]);
            const float q04 = s_t3b[zidx];
            v30c[0] += q0.x * wab; v30c[1] += q0.y * wab; v30c[2] += q0.z * wab;
            v30c[3] += q0.w * wab; v30c[4] += q04 * wab;
        }
    }

    // --- bilinear v2 (16ch), stride-20 b128 reads ---
    float v2c[16];
    {
        const float w00 = wa[0] * wb[0], w01 = wa[0] * wb[1];
        const float w10 = wa[1] * wb[0], w11 = wa[1] * wb[1];
        const float4* p00 = reinterpret_cast<const float4*>(&s_tab2[(ia * 19 + ib) * 20]);
        const float4* p01 = reinterpret_cast<const float4*>(&s_tab2[(ia * 19 + ib + 1) * 20]);
        const float4* p10 = reinterpret_cast<const float4*>(&s_tab2[((ia + 1) * 19 + ib) * 20]);
        const float4* p11 = reinterpret_cast<const float4*>(&s_tab2[((ia + 1) * 19 + ib + 1) * 20]);
#pragma unroll
        for (int q = 0; q < 4; ++q) {
            const float4 a = p00[q], b = p01[q], c = p10[q], d = p11[q];
            v2c[4 * q + 0] = a.x * w00 + b.x * w01 + c.x * w10 + d.x * w11;
            v2c[4 * q + 1] = a.y * w00 + b.y * w01 + c.y * w10 + d.y * w11;
            v2c[4 * q + 2] = a.z * w00 + b.z * w01 + c.z * w10 + d.z * w11;
            v2c[4 * q + 3] = a.w * w00 + b.w * w01 + c.w * w10 + d.w * w11;
        }
    }

    // --- linear v1 (21ch) ---
    float v1c[21];
    {
        const float* r0 = &s_tab1[ia * 21];
        const float* r1 = &s_tab1[(ia + 1) * 21];
#pragma unroll
        for (int c = 0; c < 21; ++c) v1c[c] = r0[c] * wa[0] + r1[c] * wa[1];
    }
    const float eta_el = s_tab1[420 + ie] * we[0] + s_tab1[421 + ie] * we[1];

    // --- unpack ---
    const float Cx = v3c[0], Cz = v3c[1], Cm = v3c[2], Cn = v3c[3], Cl = v3c[4];
    const float Cy = v2c[0];
    const float Cxq = v1c[0], Cyr = v1c[1], Cyp = v1c[2], Czq = v1c[3], Clr = v1c[4];
    const float Clp = v1c[5], Cmq = v1c[6], Cnr = v1c[7], Cnp = v1c[8];
    const float dCxq_lef = v1c[9], dCyr_lef = v1c[10], dCyp_lef = v1c[11];
    const float dCzq_lef = v1c[12], dClr_lef = v1c[13], dClp_lef = v1c[14];
    const float dCmq_lef = v1c[15], dCnr_lef = v1c[16], dCnp_lef = v1c[17];
    const float dCnbeta = v1c[18], dClbeta = v1c[19], dCm = v1c[20];

    const float d_Cx_lef = v2c[1] - v30c[0];
    const float d_Cz_lef = v2c[2] - v30c[1];
    const float d_Cm_lef = v2c[3] - v30c[2];
    const float d_Cy_lef = v2c[4] - v2c[0];
    const float d_Cn_lef = v2c[5] - v30c[3];
    const float d_Cl_lef = v2c[6] - v30c[4];
    const float d_Cy_r30 = v2c[7] - v2c[0];
    const float d_Cn_r30 = v2c[8] - v30c[3];
    const float d_Cl_r30 = v2c[9] - v30c[4];
    const float d_Cy_a20 = v2c[10] - v2c[0];
    const float d_Cy_a20_lef = v2c[11] - v2c[4];
    const float d_Cn_a20 = v2c[12] - v30c[3];
    const float d_Cn_a20_lef = v2c[13] - v2c[5];
    const float d_Cl_a20 = v2c[14] - v30c[4];
    const float d_Cl_a20_lef = v2c[15] - v2c[6];

    // --- kinematics ---
    const float U = vt * ca * cb, V = vt * sb, W = vt * sa * cb;
    const float o0 = U * (ct * cpsi) + V * (sphi * cpsi * st - cphi * spsi) + W * (cphi * st * cpsi + sphi * spsi);
    const float o1 = U * (ct * spsi) + V * (sphi * spsi * st + cphi * cpsi) + W * (cphi * st * spsi - sphi * cpsi);
    const float o2 = U * st - V * (sphi * ct) - W * (cphi * ct);
    const float o3 = P + tt * (Q * sphi + R * cphi);
    const float o4 = Q * cphi - R * sphi;
    const float o5 = (Q * sphi + R * cphi) / ct;

    // --- coefficients ---
    const float c2v = 1.0f / (2.0f * vt);
    const float cq = cbar * c2v, bq = Bs * c2v;
    const float dXdQ = cq * (Cxq + dCxq_lef * dlef);
    const float Cx_tot = Cx + d_Cx_lef * dlef + dXdQ * Q;
    const float dZdQ = cq * (Czq + dCzq_lef * dlef);
    const float Cz_tot = Cz + d_Cz_lef * dlef + dZdQ * Q;
    const float dMdQ = cq * (Cmq + dCmq_lef * dlef);
    const float Cm_tot = Cm * eta_el + Cz_tot * (xcgr - xcg) + d_Cm_lef * dlef + dMdQ * Q + dCm;
    const float dYdail = d_Cy_a20 + d_Cy_a20_lef * dlef;
    const float dYdR = bq * (Cyr + dCyr_lef * dlef);
    const float dYdP = bq * (Cyp + dCyp_lef * dlef);
    const float Cy_tot = Cy + d_Cy_lef * dlef + dYdail * dail + d_Cy_r30 * drud + dYdR * R + dYdP * P;
    const float dNdail = d_Cn_a20 + d_Cn_a20_lef * dlef;
    const float dNdR = bq * (Cnr + dCnr_lef * dlef);
    const float dNdP = bq * (Cnp + dCnp_lef * dlef);
    const float Cn_tot = Cn + d_Cn_lef * dlef - Cy_tot * ((xcgr - xcg) * (cbar / Bs))
                       + dNdail * dail + d_Cn_r30 * drud + dNdR * R + dNdP * P + dCnbeta * b_deg;
    const float dLdail = d_Cl_a20 + d_Cl_a20_lef * dlef;
    const float dLdR = bq * (Clr + dClr_lef * dlef);
    const float dLdP = bq * (Clp + dClp_lef * dlef);
    const float Cl_tot = Cl + d_Cl_lef * dlef + dLdail * dail + d_Cl_r30 * drud
                       + dLdR * R + dLdP * P + dClbeta * b_deg;

    // --- forces / moments ---
    const float qS = qbar * S;
    const float qS_m = qS * (1.0f / m_);
    const float Udot = R * V - Q * W - g * st + qS_m * Cx_tot + T * (1.0f / m_);
    const float Vdot = P * W - R * U + g * ct * sphi + qS_m * Cy_tot;
    const float Wdot = Q * U - P * V + g * ct * cphi + qS_m * Cz_tot;
    const float o6 = (U * Udot + V * Vdot + W * Wdot) / vt;
    const float o7 = (U * Wdot - W * Udot) / (U * U + W * W);
    const float o8 = (Vdot * vt - V * o6) / (vt * vt * cb);

    const float L_tot = Cl_tot * qS * Bs;
    const float M_tot = Cm_tot * qS * cbar;
    const float N_tot = Cn_tot * qS * Bs;
    const float denom = Jx * Jz - Jxz * Jxz;
    const float inv_denom = 1.0f / denom;
    const float o9  = (Jz * L_tot + Jxz * N_tot - (Jz * (Jz - Jy) + Jxz * Jxz) * Q * R
                      + Jxz * (Jx - Jy + Jz) * P * Q) * inv_denom;           // Heng = 0
    const float o10 = (M_tot + (Jz - Jx) * P * R - Jxz * (P * P - R * R)) * (1.0f / Jy);
    const float o11 = (Jx * N_tot + Jxz * L_tot + (Jx * (Jx - Jy) + Jxz * Jxz) * P * Q
                      - Jxz * (Jx - Jy + Jz) * Q * R) * inv_denom;

    float o[17] = {o0, o1, o2, o3, o4, o5, o6, o7, o8, o9, o10, o11,
                   0.0f, 0.0f, 0.0f, 0.0f, 0.0f};

    // ---------------- write-out, phase A then phase B --------------------------
    __syncthreads();   // all s_io reads done
    if (half == 0 && active) {
#pragma unroll
        for (int j = 0; j < 17; ++j) s_io[l * 17 + j] = o[j];
    }
    __syncthreads();
    if (rowsA == 512) {
        const float4* src = reinterpret_cast<const float4*>(s_io);
        float4* dst = reinterpret_cast<float4*>(out + (size_t)base * 17);
        for (int k = tid; k < 2176; k += BLOCK) dst[k] = src[k];
    } else {
        for (int k = tid; k < rowsA * 17; k += BLOCK) out[(size_t)base * 17 + k] = s_io[k];
    }
    __syncthreads();
    if (half == 1 && active) {
#pragma unroll
        for (int j = 0; j < 17; ++j) s_io[l * 17 + j] = o[j];
    }
    __syncthreads();
    if (rowsB == 512) {
        const float4* src = reinterpret_cast<const float4*>(s_io);
        float4* dst = reinterpret_cast<float4*>(out + (size_t)(base + 512) * 17);
        for (int k = tid; k < 2176; k += BLOCK) dst[k] = src[k];
    } else {
        for (int k = tid; k < rowsB * 17; k += BLOCK) out[(size_t)(base + 512) * 17 + k] = s_io[k];
    }
}

extern "C" void kernel_launch(void* const* d_in, const int* in_sizes, int n_in,
                              void* d_out, int out_size, void* d_ws, size_t ws_size,
                              hipStream_t stream) {
    const float* xu      = (const float*)d_in[0];
    const float* tab3    = (const float*)d_in[1];
    const float* tab2    = (const float*)d_in[2];
    const float* tab1    = (const float*)d_in[3];
    const float* tab_eta = (const float*)d_in[4];
    float* out = (float*)d_out;

    const int nrows = in_sizes[0] / 17;
    const int grid = (nrows + ROWS_PER_BLOCK - 1) / ROWS_PER_BLOCK;
    nlplant_kernel<<<grid, BLOCK, 0, stream>>>(xu, tab3, tab2, tab1, tab_eta, out, nrows);
}